// Round 6
// baseline (232.393 us; speedup 1.0000x reference)
//
#include <hip/hip_runtime.h>
#include <hip/hip_bf16.h>

#define DEV __device__ __forceinline__

typedef __attribute__((ext_vector_type(8))) short short8;
typedef __attribute__((ext_vector_type(4))) float f32x4;
typedef __attribute__((ext_vector_type(16))) float f32x16;
typedef __attribute__((ext_vector_type(2))) unsigned int u32x2;
typedef __attribute__((ext_vector_type(4))) unsigned int u32x4;
typedef unsigned short u16;
typedef unsigned int u32;

// B=4, T=2048, D=1024, H=16, E=64, M = B*T = 8192

DEV u16 f2bf(float f) {
    union { __hip_bfloat16 h; u16 u; } cv;
    cv.h = __float2bfloat16(f);
    return cv.u;
}

DEV float exp2_raw(float x) {
    float r;
    asm("v_exp_f32 %0, %1" : "=v"(r) : "v"(x));
    return r;
}

DEV u32 cvtpk_bf2(float lo, float hi) {
    u32 r;
    asm("v_cvt_pk_bf16_f32 %0, %1, %2" : "=v"(r) : "v"(lo), "v"(hi));
    return r;
}

DEV float max3f(float a, float b, float c) { return fmaxf(fmaxf(a, b), c); }

DEV void gload_lds16(const void* g, void* l) {
    __builtin_amdgcn_global_load_lds((const __attribute__((address_space(1))) u32*)g,
                                     (__attribute__((address_space(3))) u32*)l, 16, 0, 0);
}

// ---------- transpose fp32 -> bf16 : 3-way merged for Wq/Wk/Wv ----------
__global__ __launch_bounds__(256) void k_transpose_w3(const float* __restrict__ W0,
                                                      const float* __restrict__ W1,
                                                      const float* __restrict__ W2,
                                                      u16* __restrict__ O0,
                                                      u16* __restrict__ O1,
                                                      u16* __restrict__ O2) {
    __shared__ float tile[64][65];
    const int x = threadIdx.x & 63, y = threadIdx.x >> 6;
    const int which = blockIdx.z >> 4, slab_i = blockIdx.z & 15;
    const float* in = which == 0 ? W0 : (which == 1 ? W1 : W2);
    u16* out = which == 0 ? O0 : (which == 1 ? O1 : O2);
    const long slab = (long)slab_i * 1024 * 64;
    const int r0 = blockIdx.x * 64;
#pragma unroll
    for (int i = 0; i < 16; ++i) {
        int rr = y + 4 * i;
        tile[rr][x] = in[slab + (long)(r0 + rr) * 64 + x];
    }
    __syncthreads();
#pragma unroll
    for (int i = 0; i < 16; ++i) {
        int cc = y + 4 * i;
        out[slab + (long)cc * 1024 + (r0 + x)] = f2bf(tile[x][cc]);
    }
}

__global__ __launch_bounds__(256) void k_transpose_f32_bf16(const float* __restrict__ in,
                                                            u16* __restrict__ out,
                                                            int R, int C) {
    __shared__ float tile[64][65];
    const int x = threadIdx.x & 63, y = threadIdx.x >> 6;
    const long slab = (long)blockIdx.z * R * C;
    const int r0 = blockIdx.x * 64, c0 = blockIdx.y * 64;
#pragma unroll
    for (int i = 0; i < 16; ++i) {
        int rr = y + 4 * i;
        tile[rr][x] = in[slab + (long)(r0 + rr) * C + (c0 + x)];
    }
    __syncthreads();
#pragma unroll
    for (int i = 0; i < 16; ++i) {
        int cc = y + 4 * i;
        out[slab + (long)(c0 + cc) * R + (r0 + x)] = f2bf(tile[x][cc]);
    }
}

// ---------- transpose bf16 -> bf16 ----------
__global__ __launch_bounds__(256) void k_transpose_bf16(const u16* __restrict__ in,
                                                        u16* __restrict__ out,
                                                        int R, int C) {
    __shared__ u16 tile[64][65];
    const int x = threadIdx.x & 63, y = threadIdx.x >> 6;
    const long slab = (long)blockIdx.z * R * C;
    const int r0 = blockIdx.x * 64, c0 = blockIdx.y * 64;
#pragma unroll
    for (int i = 0; i < 16; ++i) {
        int rr = y + 4 * i;
        tile[rr][x] = in[slab + (long)(r0 + rr) * C + (c0 + x)];
    }
    __syncthreads();
#pragma unroll
    for (int i = 0; i < 16; ++i) {
        int cc = y + 4 * i;
        out[slab + (long)(c0 + cc) * R + (r0 + x)] = tile[x][cc];
    }
}

// ---------- GEMM v2: BM=256, BN=128, BK=64, 512 thr (8 waves = 4M x 2N) ----------
// LDS [256][64] + [128][64] bf16, double-buffered (96KB). Row = 128B = 8 slots of
// 16B; swizzle slot s' = s ^ (row&7) -> conflict-free b128 frag reads.
// One barrier + full drain per K-tile (flight = 32 MFMA + frag reads).
// XCD chunked blockIdx swizzle: consecutive logical blocks share the A panel.

// merged Q/K/V projection: A fp32 reg-staged (cvt_pk), B via gload_lds
__global__ __launch_bounds__(512) void k_gemm3(const float* __restrict__ A0, const float* __restrict__ A1,
                                               const float* __restrict__ A2,
                                               const u16* __restrict__ B0, const u16* __restrict__ B1,
                                               const u16* __restrict__ B2,
                                               u16* __restrict__ C0, u16* __restrict__ C1,
                                               u16* __restrict__ C2) {
    __shared__ u16 As[2][16384];   // [256][64]
    __shared__ u16 Bs[2][8192];    // [128][64]
    const int tid = threadIdx.x, lane = tid & 63, w = tid >> 6;
    const int l15 = lane & 15, l4 = lane >> 4;
    const int wr = w >> 1, wc = w & 1;
    // XCD chunk swizzle over 768 blocks (768 % 8 == 0; q = 96)
    const int hw = blockIdx.x;
    const int lg = (hw & 7) * 96 + (hw >> 3);
    const int z = lg >> 8, rem = lg & 255;
    const int brow = (rem >> 3) * 256, bcol = (rem & 7) * 128;
    const float* Af = z == 0 ? A0 : (z == 1 ? A1 : A2);
    const u16*   Bt = z == 0 ? B0 : (z == 1 ? B1 : B2);
    u16*         Cb = z == 0 ? C0 : (z == 1 ? C1 : C2);

    // A reg-stage: 4 chunks/thread (chunk = 16B LDS = 8 bf16 <- 32B fp32)
    const float* aptr[4];
    int adst[4];
#pragma unroll
    for (int i = 0; i < 4; ++i) {
        const int c = tid + i * 512;
        const int r = c >> 3, s = c & 7, sw = s ^ (r & 7);
        aptr[i] = Af + (long)(brow + r) * 1024 + s * 8;   // unswizzled src, swizzled dst
        adst[i] = r * 64 + sw * 8;
    }
    // B gload: 2 instr/thread, linear dest + pre-swizzled source
    const u16* bptr[2];
    int bdst[2];
#pragma unroll
    for (int i = 0; i < 2; ++i) {
        const int c = i * 512 + w * 64 + lane;
        const int r = c >> 3, s = c & 7, sw = s ^ (r & 7);
        bptr[i] = Bt + (long)(bcol + r) * 1024 + sw * 8;
        bdst[i] = i * 4096 + w * 512;                     // wave-uniform elem base
    }

    // frag offsets (row&7 == l15&7 everywhere)
    int e4[2];
#pragma unroll
    for (int kk = 0; kk < 2; ++kk) e4[kk] = ((kk * 4 + l4) ^ (l15 & 7)) * 8;
    int offA[4][2], offB[4][2];
#pragma unroll
    for (int m = 0; m < 4; ++m)
#pragma unroll
        for (int kk = 0; kk < 2; ++kk) {
            offA[m][kk] = (wr * 64 + m * 16 + l15) * 64 + e4[kk];
            offB[m][kk] = (wc * 64 + m * 16 + l15) * 64 + e4[kk];
        }

    f32x4 acc[4][4] = {};
    float4 va[8];

    // prologue: tile 0
    gload_lds16(bptr[0], &Bs[0][bdst[0]]);
    gload_lds16(bptr[1], &Bs[0][bdst[1]]);
#pragma unroll
    for (int i = 0; i < 4; ++i) {
        va[2 * i]     = *(const float4*)(aptr[i]);
        va[2 * i + 1] = *(const float4*)(aptr[i] + 4);
    }
#pragma unroll
    for (int i = 0; i < 4; ++i) {
        u32x4 wv;
        wv[0] = cvtpk_bf2(va[2 * i].x, va[2 * i].y);
        wv[1] = cvtpk_bf2(va[2 * i].z, va[2 * i].w);
        wv[2] = cvtpk_bf2(va[2 * i + 1].x, va[2 * i + 1].y);
        wv[3] = cvtpk_bf2(va[2 * i + 1].z, va[2 * i + 1].w);
        *(u32x4*)&As[0][adst[i]] = wv;
    }

#pragma unroll 2
    for (int t = 0; t < 16; ++t) {
        const int buf = t & 1;
        __syncthreads();               // tile t staged (vm+lgkm drained); WAR-safe
        if (t < 15) {                  // issue next-tile loads: flight = this tile's compute
            const int ko = (t + 1) * 64;
            gload_lds16(bptr[0] + ko, &Bs[buf ^ 1][bdst[0]]);
            gload_lds16(bptr[1] + ko, &Bs[buf ^ 1][bdst[1]]);
#pragma unroll
            for (int i = 0; i < 4; ++i) {
                va[2 * i]     = *(const float4*)(aptr[i] + ko);
                va[2 * i + 1] = *(const float4*)(aptr[i] + ko + 4);
            }
        }

        short8 af[4][2], bfv[4][2];
#pragma unroll
        for (int m = 0; m < 4; ++m)
#pragma unroll
            for (int kk = 0; kk < 2; ++kk) {
                af[m][kk]  = *(const short8*)&As[buf][offA[m][kk]];
                bfv[m][kk] = *(const short8*)&Bs[buf][offB[m][kk]];
            }
#pragma unroll
        for (int m = 0; m < 4; ++m)
#pragma unroll
            for (int n = 0; n < 4; ++n)
#pragma unroll
                for (int kk = 0; kk < 2; ++kk)
                    acc[m][n] = __builtin_amdgcn_mfma_f32_16x16x32_bf16(af[m][kk], bfv[n][kk], acc[m][n], 0, 0, 0);

        if (t < 15) {                  // convert + write A tile t+1 (after MFMA issue)
#pragma unroll
            for (int i = 0; i < 4; ++i) {
                u32x4 wv;
                wv[0] = cvtpk_bf2(va[2 * i].x, va[2 * i].y);
                wv[1] = cvtpk_bf2(va[2 * i].z, va[2 * i].w);
                wv[2] = cvtpk_bf2(va[2 * i + 1].x, va[2 * i + 1].y);
                wv[3] = cvtpk_bf2(va[2 * i + 1].z, va[2 * i + 1].w);
                *(u32x4*)&As[buf ^ 1][adst[i]] = wv;
            }
        }
    }

    // epilogue: C bf16 [b][h][t][e]; D lane layout row=(l4*4+r), col=l15
#pragma unroll
    for (int m = 0; m < 4; ++m)
#pragma unroll
        for (int n = 0; n < 4; ++n)
#pragma unroll
            for (int r = 0; r < 4; ++r) {
                const int trow = brow + wr * 64 + m * 16 + l4 * 4 + r;
                const int ncol = bcol + wc * 64 + n * 16 + l15;
                const int b = trow >> 11, tt = trow & 2047;
                const int h = ncol >> 6, e = ncol & 63;
                Cb[(long)(b * 16 + h) * 131072 + (long)tt * 64 + e] = f2bf(acc[m][n][r]);
            }
}

// output projection: A = bf16 attn [bh][t][e] (K-tile == head), all-gload_lds; C fp32
__global__ __launch_bounds__(512) void k_gemm_out(const u16* __restrict__ Ab,
                                                  const u16* __restrict__ Bt,
                                                  float* __restrict__ Cf) {
    __shared__ u16 As[2][16384];   // [256][64]
    __shared__ u16 Bs[2][8192];    // [128][64]
    const int tid = threadIdx.x, lane = tid & 63, w = tid >> 6;
    const int l15 = lane & 15, l4 = lane >> 4;
    const int wr = w >> 1, wc = w & 1;
    const int hw = blockIdx.x;                    // 256 blocks, q = 32
    const int lg = (hw & 7) * 32 + (hw >> 3);
    const int brow = (lg >> 3) * 256, bcol = (lg & 7) * 128;

    // A gload: 4 instr/thread; per K-tile the head index == t
    const u16* aptr[4];
    int adst[4];
#pragma unroll
    for (int i = 0; i < 4; ++i) {
        const int c = i * 512 + w * 64 + lane;
        const int r = c >> 3, s = c & 7, sw = s ^ (r & 7);
        const int g = brow + r, b = g >> 11, tt = g & 2047;
        aptr[i] = Ab + (long)(b * 16) * 131072 + (long)tt * 64 + sw * 8;  // + t*131072
        adst[i] = i * 4096 + w * 512;
    }
    const u16* bptr[2];
    int bdst[2];
#pragma unroll
    for (int i = 0; i < 2; ++i) {
        const int c = i * 512 + w * 64 + lane;
        const int r = c >> 3, s = c & 7, sw = s ^ (r & 7);
        bptr[i] = Bt + (long)(bcol + r) * 1024 + sw * 8;
        bdst[i] = i * 4096 + w * 512;
    }

    int e4[2];
#pragma unroll
    for (int kk = 0; kk < 2; ++kk) e4[kk] = ((kk * 4 + l4) ^ (l15 & 7)) * 8;
    int offA[4][2], offB[4][2];
#pragma unroll
    for (int m = 0; m < 4; ++m)
#pragma unroll
        for (int kk = 0; kk < 2; ++kk) {
            offA[m][kk] = (wr * 64 + m * 16 + l15) * 64 + e4[kk];
            offB[m][kk] = (wc * 64 + m * 16 + l15) * 64 + e4[kk];
        }

    f32x4 acc[4][4] = {};

#define STAGE_O(buf, t) do {                                       \
    const long ao = (long)(t) * 131072;                            \
    const int  ko = (t) * 64;                                      \
    gload_lds16(aptr[0] + ao, &As[buf][adst[0]]);                  \
    gload_lds16(aptr[1] + ao, &As[buf][adst[1]]);                  \
    gload_lds16(aptr[2] + ao, &As[buf][adst[2]]);                  \
    gload_lds16(aptr[3] + ao, &As[buf][adst[3]]);                  \
    gload_lds16(bptr[0] + ko, &Bs[buf][bdst[0]]);                  \
    gload_lds16(bptr[1] + ko, &Bs[buf][bdst[1]]);                  \
  } while (0)

    STAGE_O(0, 0);

#pragma unroll 2
    for (int t = 0; t < 16; ++t) {
        const int buf = t & 1;
        __syncthreads();
        if (t < 15) STAGE_O(buf ^ 1, t + 1);

        short8 af[4][2], bfv[4][2];
#pragma unroll
        for (int m = 0; m < 4; ++m)
#pragma unroll
            for (int kk = 0; kk < 2; ++kk) {
                af[m][kk]  = *(const short8*)&As[buf][offA[m][kk]];
                bfv[m][kk] = *(const short8*)&Bs[buf][offB[m][kk]];
            }
#pragma unroll
        for (int m = 0; m < 4; ++m)
#pragma unroll
            for (int n = 0; n < 4; ++n)
#pragma unroll
                for (int kk = 0; kk < 2; ++kk)
                    acc[m][n] = __builtin_amdgcn_mfma_f32_16x16x32_bf16(af[m][kk], bfv[n][kk], acc[m][n], 0, 0, 0);
    }
#undef STAGE_O

#pragma unroll
    for (int m = 0; m < 4; ++m)
#pragma unroll
        for (int n = 0; n < 4; ++n)
#pragma unroll
            for (int r = 0; r < 4; ++r) {
                const int trow = brow + wr * 64 + m * 16 + l4 * 4 + r;
                const int ncol = bcol + wc * 64 + n * 16 + l15;
                Cf[(long)trow * 1024 + ncol] = acc[m][n][r];
            }
}

// ---------- flash attention v4: 32x32 MFMA, in-register softmax, lean VALU ----------
__global__ __launch_bounds__(256, 4) void k_flash4(const u16* __restrict__ Qh,
                                                   const u16* __restrict__ Kh,
                                                   const u16* __restrict__ VhT,
                                                   u16* __restrict__ attn) {
    __shared__ u16 Ks[2][4096];   // [kv][d], 16B chunks XOR-swizzled by row&7
    __shared__ u16 Vs[2][4096];   // [e][kv], same swizzle

    const int tid = threadIdx.x, lane = tid & 63, w = tid >> 6;
    const int l31 = lane & 31, l5 = lane >> 5;
    const int wid = blockIdx.x;
    const int swz = (wid & 7) * 128 + (wid >> 3);   // bijective: 1024 % 8 == 0
    const int bh = swz >> 4, qt = swz & 15;
    const long base = (long)bh * (2048 * 64);
    const int q = qt * 128 + w * 32 + l31;          // this lane's q row

    short8 qf[4];
    {
        const u16* qp = Qh + base + (long)q * 64 + l5 * 8;
#pragma unroll
        for (int ksd = 0; ksd < 4; ++ksd) qf[ksd] = *(const short8*)(qp + ksd * 16);
    }

    int off[4];
#pragma unroll
    for (int ksd = 0; ksd < 4; ++ksd)
        off[ksd] = l31 * 128 + (((ksd * 2 + l5) ^ (l31 & 7)) << 4);

    const float CEXP = 0.18033688011112042f;   // 0.125 * log2(e)
    float mr = -INFINITY;
    f32x16 oacc0 = {}, oacc1 = {}, lacc = {};

    short8 ones;
#pragma unroll
    for (int j = 0; j < 8; ++j) ones[j] = (short)0x3F80;

    const int c0 = tid, c1 = tid + 256;
    const int r0 = c0 >> 3, s0 = (c0 & 7) ^ (r0 & 7);
    const int r1 = c1 >> 3, s1 = (c1 & 7) ^ (r1 & 7);

#define STAGE(buf, t) do {                                                              \
    const long kv0_ = (long)((t) * 64);                                                 \
    gload_lds16(Kh + base + (kv0_ + r0) * 64 + s0 * 8, &Ks[buf][w * 512]);              \
    gload_lds16(Kh + base + (kv0_ + r1) * 64 + s1 * 8, &Ks[buf][2048 + w * 512]);       \
    gload_lds16(VhT + base + (long)r0 * 2048 + kv0_ + s0 * 8, &Vs[buf][w * 512]);       \
    gload_lds16(VhT + base + (long)r1 * 2048 + kv0_ + s1 * 8, &Vs[buf][2048 + w * 512]); \
  } while (0)

    STAGE(0, 0);

#pragma unroll 2
    for (int t = 0; t < 32; ++t) {
        const int buf = t & 1;
        __syncthreads();
        if (t < 31) STAGE(buf ^ 1, t + 1);

        const char* Kb = (const char*)&Ks[buf][0];
        const char* Vb = (const char*)&Vs[buf][0];

        f32x16 z0 = {}, z1 = {};
#pragma unroll
        for (int ksd = 0; ksd < 4; ++ksd) {
            short8 kf0 = *(const short8*)(Kb + off[ksd]);
            z0 = __builtin_amdgcn_mfma_f32_32x32x16_bf16(kf0, qf[ksd], z0, 0, 0, 0);
            short8 kf1 = *(const short8*)(Kb + 4096 + off[ksd]);
            z1 = __builtin_amdgcn_mfma_f32_32x32x16_bf16(kf1, qf[ksd], z1, 0, 0, 0);
        }

        float a0 = max3f(z0[0],  z0[1],  z0[2]);
        float a1 = max3f(z0[3],  z0[4],  z0[5]);
        float a2 = max3f(z0[6],  z0[7],  z0[8]);
        float a3 = max3f(z0[9],  z0[10], z0[11]);
        float a4 = max3f(z0[12], z0[13], z0[14]);
        float a5 = max3f(z0[15], z1[0],  z1[1]);
        float a6 = max3f(z1[2],  z1[3],  z1[4]);
        float a7 = max3f(z1[5],  z1[6],  z1[7]);
        float a8 = max3f(z1[8],  z1[9],  z1[10]);
        float a9 = max3f(z1[11], z1[12], z1[13]);
        float aa = fmaxf(z1[14], z1[15]);
        float b0 = max3f(a0, a1, a2);
        float b1 = max3f(a3, a4, a5);
        float b2 = max3f(a6, a7, a8);
        float b3 = fmaxf(a9, aa);
        float vm = fmaxf(max3f(b0, b1, b2), b3);
        {
            u32x2 pp = __builtin_amdgcn_permlane32_swap(__builtin_bit_cast(u32, vm),
                                                        __builtin_bit_cast(u32, vm), false, false);
            vm = fmaxf(__builtin_bit_cast(float, pp[0]), __builtin_bit_cast(float, pp[1]));
        }
        if (!__all(vm - mr <= 8.0f)) {     // T13 defer-max (raw THR=8 -> P <= e)
            const float nm = fmaxf(mr, vm);
            const float sc = exp2_raw((mr - nm) * CEXP);
            mr = nm;
#pragma unroll
            for (int i = 0; i < 16; ++i) { oacc0[i] *= sc; oacc1[i] *= sc; }
            lacc[0] *= sc;
        }
        const float nmc = -mr * CEXP;

#pragma unroll
        for (int tile = 0; tile < 2; ++tile) {
            const f32x16& zz = tile ? z1 : z0;
            u32 W[8];
#pragma unroll
            for (int mw = 0; mw < 8; ++mw) {
                const float p0 = exp2_raw(fmaf(zz[2 * mw],     CEXP, nmc));
                const float p1 = exp2_raw(fmaf(zz[2 * mw + 1], CEXP, nmc));
                W[mw] = cvtpk_bf2(p0, p1);
            }
#pragma unroll
            for (int ksw = 0; ksw < 2; ++ksw) {
                const int ks = tile * 2 + ksw;
                u32x2 ra = __builtin_amdgcn_permlane32_swap(W[4 * ksw + 0], W[4 * ksw + 2], false, false);
                u32x2 rb = __builtin_amdgcn_permlane32_swap(W[4 * ksw + 1], W[4 * ksw + 3], false, false);
                u32x4 pw; pw[0] = ra[0]; pw[1] = rb[0]; pw[2] = ra[1]; pw[3] = rb[1];
                const short8 pb = __builtin_bit_cast(short8, pw);
                short8 vf0 = *(const short8*)(Vb + off[ks]);
                oacc0 = __builtin_amdgcn_mfma_f32_32x32x16_bf16(vf0, pb, oacc0, 0, 0, 0);
                short8 vf1 = *(const short8*)(Vb + 4096 + off[ks]);
                oacc1 = __builtin_amdgcn_mfma_f32_32x32x16_bf16(vf1, pb, oacc1, 0, 0, 0);
                lacc = __builtin_amdgcn_mfma_f32_32x32x16_bf16(ones, pb, lacc, 0, 0, 0);
            }
        }
    }
#undef STAGE

    const float inv = 1.0f / lacc[0];
    u16* op = attn + base + (long)q * 64;
#pragma unroll
    for (int et = 0; et < 2; ++et) {
        const f32x16& oa = et ? oacc1 : oacc0;
#pragma unroll
        for (int rq = 0; rq < 4; ++rq) {
            u32x2 st;
            st[0] = cvtpk_bf2(oa[4 * rq + 0] * inv, oa[4 * rq + 1] * inv);
            st[1] = cvtpk_bf2(oa[4 * rq + 2] * inv, oa[4 * rq + 3] * inv);
            *(u32x2*)(op + et * 32 + rq * 8 + l5 * 4) = st;
        }
    }
}

extern "C" void kernel_launch(void* const* d_in, const int* in_sizes, int n_in,
                              void* d_out, int out_size, void* d_ws, size_t ws_size,
                              hipStream_t stream) {
    (void)in_sizes; (void)n_in; (void)out_size; (void)ws_size;
    const float* Q  = (const float*)d_in[0];
    const float* K  = (const float*)d_in[1];
    const float* V  = (const float*)d_in[2];
    const float* Wq = (const float*)d_in[3];
    const float* Wk = (const float*)d_in[4];
    const float* Wv = (const float*)d_in[5];
    const float* Wo = (const float*)d_in[6];

    char* ws = (char*)d_ws;
    auto WS = [&](size_t mb) { return (u16*)(ws + (mb << 20)); };
    u16* WqT  = WS(0);    // [1024][1024] bf16 (B^T layouts)   2MB each
    u16* WkT  = WS(2);
    u16* WvT  = WS(4);
    u16* WoT  = WS(6);
    u16* Qh   = WS(8);    // [64][2048][64] bf16   16MB each
    u16* Kh   = WS(24);
    u16* Vh   = WS(40);
    u16* VhT  = WS(56);   // [64][64][2048]
    u16* attn = WS(72);   // [64][2048][64]        ends at 88MB

    dim3 b256(256);
    dim3 b512(512);
    // weights -> B^T bf16. Wq/Wk/Wv merged: per head [1024d][64e] -> [64e][1024d]
    k_transpose_w3<<<dim3(16, 1, 48), b256, 0, stream>>>(Wq, Wk, Wv, WqT, WkT, WvT);
    // Wo: [1024 he][1024 D] -> [1024 D][1024 he]
    k_transpose_f32_bf16<<<dim3(16, 16, 1), b256, 0, stream>>>(Wo, WoT, 1024, 1024);

    // merged Q/K/V projections (768 blocks = 3 exact CU rounds)
    k_gemm3<<<dim3(768), b512, 0, stream>>>(Q, K, V, WqT, WkT, WvT, Qh, Kh, Vh);

    // V transpose per (b,h): [2048][64] -> [64][2048]
    k_transpose_bf16<<<dim3(32, 1, 64), b256, 0, stream>>>(Vh, VhT, 2048, 64);

    // attention
    k_flash4<<<dim3(1024), b256, 0, stream>>>(Qh, Kh, VhT, attn);

    // output projection (256 blocks = 1 exact CU round)
    k_gemm_out<<<dim3(256), b512, 0, stream>>>(attn, WoT, (float*)d_out);
}

// Round 7
// 229.311 us; speedup vs baseline: 1.0134x; 1.0134x over previous
//
#include <hip/hip_runtime.h>
#include <hip/hip_bf16.h>

#define DEV __device__ __forceinline__

typedef __attribute__((ext_vector_type(8))) short short8;
typedef __attribute__((ext_vector_type(4))) float f32x4;
typedef __attribute__((ext_vector_type(16))) float f32x16;
typedef __attribute__((ext_vector_type(2))) unsigned int u32x2;
typedef __attribute__((ext_vector_type(4))) unsigned int u32x4;
typedef unsigned short u16;
typedef unsigned int u32;

// B=4, T=2048, D=1024, H=16, E=64, M = B*T = 8192

DEV u16 f2bf(float f) {
    union { __hip_bfloat16 h; u16 u; } cv;
    cv.h = __float2bfloat16(f);
    return cv.u;
}

DEV float exp2_raw(float x) {
    float r;
    asm("v_exp_f32 %0, %1" : "=v"(r) : "v"(x));
    return r;
}

DEV u32 cvtpk_bf2(float lo, float hi) {
    u32 r;
    asm("v_cvt_pk_bf16_f32 %0, %1, %2" : "=v"(r) : "v"(lo), "v"(hi));
    return r;
}

DEV float max3f(float a, float b, float c) { return fmaxf(fmaxf(a, b), c); }

DEV void gload_lds16(const void* g, void* l) {
    __builtin_amdgcn_global_load_lds((const __attribute__((address_space(1))) u32*)g,
                                     (__attribute__((address_space(3))) u32*)l, 16, 0, 0);
}

// ---------- fp32 -> bf16 convert, 3 tensors (8192*1024 each) ----------
__global__ __launch_bounds__(256) void k_cvt3(const float* __restrict__ A0, const float* __restrict__ A1,
                                              const float* __restrict__ A2,
                                              u16* __restrict__ O0, u16* __restrict__ O1,
                                              u16* __restrict__ O2) {
    const int z = blockIdx.z;
    const float* X = z == 0 ? A0 : (z == 1 ? A1 : A2);
    u16* Y = z == 0 ? O0 : (z == 1 ? O1 : O2);
    const int t0 = blockIdx.x * 256 + threadIdx.x;     // 1024 blocks * 256 thr
#pragma unroll
    for (int i = 0; i < 4; ++i) {
        const long c = ((long)i * 262144 + t0) * 8;    // 8 elems/chunk
        float4 v0 = *(const float4*)(X + c);
        float4 v1 = *(const float4*)(X + c + 4);
        u32x4 wv;
        wv[0] = cvtpk_bf2(v0.x, v0.y); wv[1] = cvtpk_bf2(v0.z, v0.w);
        wv[2] = cvtpk_bf2(v1.x, v1.y); wv[3] = cvtpk_bf2(v1.z, v1.w);
        *(u32x4*)(Y + c) = wv;
    }
}

// ---------- transpose fp32 -> bf16 : 3-way merged for Wq/Wk/Wv ----------
__global__ __launch_bounds__(256) void k_transpose_w3(const float* __restrict__ W0,
                                                      const float* __restrict__ W1,
                                                      const float* __restrict__ W2,
                                                      u16* __restrict__ O0,
                                                      u16* __restrict__ O1,
                                                      u16* __restrict__ O2) {
    __shared__ float tile[64][65];
    const int x = threadIdx.x & 63, y = threadIdx.x >> 6;
    const int which = blockIdx.z >> 4, slab_i = blockIdx.z & 15;
    const float* in = which == 0 ? W0 : (which == 1 ? W1 : W2);
    u16* out = which == 0 ? O0 : (which == 1 ? O1 : O2);
    const long slab = (long)slab_i * 1024 * 64;
    const int r0 = blockIdx.x * 64;
#pragma unroll
    for (int i = 0; i < 16; ++i) {
        int rr = y + 4 * i;
        tile[rr][x] = in[slab + (long)(r0 + rr) * 64 + x];
    }
    __syncthreads();
#pragma unroll
    for (int i = 0; i < 16; ++i) {
        int cc = y + 4 * i;
        out[slab + (long)cc * 1024 + (r0 + x)] = f2bf(tile[x][cc]);
    }
}

__global__ __launch_bounds__(256) void k_transpose_f32_bf16(const float* __restrict__ in,
                                                            u16* __restrict__ out,
                                                            int R, int C) {
    __shared__ float tile[64][65];
    const int x = threadIdx.x & 63, y = threadIdx.x >> 6;
    const long slab = (long)blockIdx.z * R * C;
    const int r0 = blockIdx.x * 64, c0 = blockIdx.y * 64;
#pragma unroll
    for (int i = 0; i < 16; ++i) {
        int rr = y + 4 * i;
        tile[rr][x] = in[slab + (long)(r0 + rr) * C + (c0 + x)];
    }
    __syncthreads();
#pragma unroll
    for (int i = 0; i < 16; ++i) {
        int cc = y + 4 * i;
        out[slab + (long)(c0 + cc) * R + (r0 + x)] = f2bf(tile[x][cc]);
    }
}

// ---------- V transpose: Vp [8192][1024] (per bh window) -> VhT [bh][64 e][2048 t] ----------
__global__ __launch_bounds__(256) void k_transpose_v(const u16* __restrict__ Vp,
                                                     u16* __restrict__ VhT) {
    __shared__ u16 tile[64][65];
    const int x = threadIdx.x & 63, y = threadIdx.x >> 6;
    const int bh = blockIdx.z, b = bh >> 4, h = bh & 15;
    const int t0 = blockIdx.x * 64;
#pragma unroll
    for (int i = 0; i < 16; ++i) {
        int rr = y + 4 * i;
        tile[rr][x] = Vp[(long)(b * 2048 + t0 + rr) * 1024 + h * 64 + x];
    }
    __syncthreads();
#pragma unroll
    for (int i = 0; i < 16; ++i) {
        int cc = y + 4 * i;
        VhT[(long)bh * 131072 + (long)cc * 2048 + t0 + x] = tile[x][cc];
    }
}

// ---------- GEMM v3: counted-vmcnt schedule (T3+T4+T5) ----------
// BM=256, BN=128, BK=64, 512 thr (8 waves = 4M x 2N), per-wave 64x64.
// LDS [256][64]+[128][64] bf16 dbuf = 96KB, slot swizzle s^(row&7) (conflict-free).
// Pipeline: stage 2 K-tiles ahead; vmcnt(6) retires only the tile being consumed;
// raw s_barrier (NOT __syncthreads -> no full drain). 2 phases/K-tile of 16 MFMA.
template<int CMODE>   // 0: C bf16, 1: C fp32
DEV void gemm8_body(const u16* __restrict__ Ap, const u16* __restrict__ Btp,
                    void* __restrict__ Cp, u16* __restrict__ As, u16* __restrict__ Bs,
                    int brow, int bcol) {
    const int tid = threadIdx.x, lane = tid & 63, w = tid >> 6;
    const int l15 = lane & 15, l4 = lane >> 4;
    const int wr = w >> 1, wc = w & 1;

    // staging: A 4 chunks/thread, B 2 chunks/thread (chunk = 16B; row = 8 chunks)
    const u16* aptr[4]; int adst[4];
#pragma unroll
    for (int i = 0; i < 4; ++i) {
        const int c = i * 512 + w * 64 + lane;
        const int r = c >> 3, s = c & 7, sw = s ^ (r & 7);
        aptr[i] = Ap + (long)(brow + r) * 1024 + sw * 8;   // pre-swizzled source
        adst[i] = i * 4096 + w * 512;                      // linear dest (wave base)
    }
    const u16* bptr[2]; int bdst[2];
#pragma unroll
    for (int i = 0; i < 2; ++i) {
        const int c = i * 512 + w * 64 + lane;
        const int r = c >> 3, s = c & 7, sw = s ^ (r & 7);
        bptr[i] = Btp + (long)(bcol + r) * 1024 + sw * 8;
        bdst[i] = i * 4096 + w * 512;
    }

    auto stage = [&](int buf, int kt) {
        const int ko = kt * 64;
        u16* Ad = As + buf * 16384;
        u16* Bd = Bs + buf * 8192;
#pragma unroll
        for (int i = 0; i < 4; ++i) gload_lds16(aptr[i] + ko, Ad + adst[i]);
#pragma unroll
        for (int i = 0; i < 2; ++i) gload_lds16(bptr[i] + ko, Bd + bdst[i]);
    };

    int e4[2];
#pragma unroll
    for (int kk = 0; kk < 2; ++kk) e4[kk] = ((kk * 4 + l4) ^ (l15 & 7)) * 8;
    int offA[4][2], offB[4][2];
#pragma unroll
    for (int m = 0; m < 4; ++m)
#pragma unroll
        for (int kk = 0; kk < 2; ++kk) {
            offA[m][kk] = (wr * 64 + m * 16 + l15) * 64 + e4[kk];
            offB[m][kk] = (wc * 64 + m * 16 + l15) * 64 + e4[kk];
        }

    f32x4 acc[4][4] = {};
    stage(0, 0);
    stage(1, 1);          // 12 loads in flight

    for (int t = 0; t < 16; ++t) {
        const int buf = t & 1;
        // retire ONLY tile t's 6 loads; tile t+1's 6 stay in flight across the barrier
        if (t < 15) asm volatile("s_waitcnt vmcnt(6)" ::: "memory");
        else        asm volatile("s_waitcnt vmcnt(0)" ::: "memory");
        __builtin_amdgcn_sched_barrier(0);
        __builtin_amdgcn_s_barrier();
        __builtin_amdgcn_sched_barrier(0);

        const u16* Ab = As + buf * 16384;
        const u16* Bb = Bs + buf * 8192;
#pragma unroll
        for (int kk = 0; kk < 2; ++kk) {
            short8 af[4], bfv[4];
#pragma unroll
            for (int m = 0; m < 4; ++m) af[m] = *(const short8*)&Ab[offA[m][kk]];
#pragma unroll
            for (int n = 0; n < 4; ++n) bfv[n] = *(const short8*)&Bb[offB[n][kk]];
            asm volatile("s_waitcnt lgkmcnt(0)" ::: "memory");
            __builtin_amdgcn_sched_barrier(0);
            __builtin_amdgcn_s_setprio(1);
#pragma unroll
            for (int m = 0; m < 4; ++m)
#pragma unroll
                for (int n = 0; n < 4; ++n)
                    acc[m][n] = __builtin_amdgcn_mfma_f32_16x16x32_bf16(af[m], bfv[n], acc[m][n], 0, 0, 0);
            __builtin_amdgcn_s_setprio(0);
            __builtin_amdgcn_sched_barrier(0);
        }
        __builtin_amdgcn_s_barrier();      // all waves done reading buf
        __builtin_amdgcn_sched_barrier(0);
        if (t + 2 < 16) stage(buf, t + 2); // refill freed buffer
    }

    // epilogue: D lane layout row=(l4*4+r), col=l15; C plain [8192][1024]
#pragma unroll
    for (int m = 0; m < 4; ++m)
#pragma unroll
        for (int n = 0; n < 4; ++n)
#pragma unroll
            for (int r = 0; r < 4; ++r) {
                const long row = brow + wr * 64 + m * 16 + l4 * 4 + r;
                const int col = bcol + wc * 64 + n * 16 + l15;
                if (CMODE == 0) ((u16*)Cp)[row * 1024 + col] = f2bf(acc[m][n][r]);
                else            ((float*)Cp)[row * 1024 + col] = acc[m][n][r];
            }
}

// merged Q/K/V projection: 768 blocks = 3 exact CU rounds, XCD-chunked
__global__ __launch_bounds__(512) void k_gemm3(const u16* __restrict__ Xq, const u16* __restrict__ Xk,
                                               const u16* __restrict__ Xv,
                                               const u16* __restrict__ B0, const u16* __restrict__ B1,
                                               const u16* __restrict__ B2,
                                               u16* __restrict__ C0, u16* __restrict__ C1,
                                               u16* __restrict__ C2) {
    __shared__ u16 As[2 * 16384];
    __shared__ u16 Bs[2 * 8192];
    const int hw = blockIdx.x;
    const int lg = (hw & 7) * 96 + (hw >> 3);      // bijective: 768 % 8 == 0
    const int z = lg >> 8, rem = lg & 255;
    const int brow = (rem >> 3) * 256, bcol = (rem & 7) * 128;
    const u16* A = z == 0 ? Xq : (z == 1 ? Xk : Xv);
    const u16* Bt = z == 0 ? B0 : (z == 1 ? B1 : B2);
    u16*       C = z == 0 ? C0 : (z == 1 ? C1 : C2);
    gemm8_body<0>(A, Bt, C, As, Bs, brow, bcol);
}

// output projection: attn [8192][1024] bf16 x WoT -> fp32 out; 256 blocks = 1 round
__global__ __launch_bounds__(512) void k_gemm_out(const u16* __restrict__ Ab,
                                                  const u16* __restrict__ Bt,
                                                  float* __restrict__ Cf) {
    __shared__ u16 As[2 * 16384];
    __shared__ u16 Bs[2 * 8192];
    const int hw = blockIdx.x;
    const int lg = (hw & 7) * 32 + (hw >> 3);      // 256 % 8 == 0
    const int brow = (lg >> 3) * 256, bcol = (lg & 7) * 128;
    gemm8_body<1>(Ab, Bt, Cf, As, Bs, brow, bcol);
}

// ---------- flash attention v4: 32x32 MFMA, in-register softmax, lean VALU ----------
// layouts: Qp/Kp/attn = [8192][1024] (row = b*2048+t, cols h*64..h*64+63); VhT = [bh][64][2048]
__global__ __launch_bounds__(256, 4) void k_flash4(const u16* __restrict__ Qp,
                                                   const u16* __restrict__ Kp,
                                                   const u16* __restrict__ VhT,
                                                   u16* __restrict__ attn) {
    __shared__ u16 Ks[2][4096];   // [kv][d], 16B chunks XOR-swizzled by row&7
    __shared__ u16 Vs[2][4096];   // [e][kv], same swizzle

    const int tid = threadIdx.x, lane = tid & 63, w = tid >> 6;
    const int l31 = lane & 31, l5 = lane >> 5;
    const int wid = blockIdx.x;
    const int swz = (wid & 7) * 128 + (wid >> 3);   // bijective: 1024 % 8 == 0
    const int bh = swz >> 4, qt = swz & 15;
    const int b = bh >> 4, h = bh & 15;
    const long rowb = (long)b * 2048;
    const int colb = h * 64;
    const u16* Kbase = Kp + rowb * 1024 + colb;
    const long vbase = (long)bh * 131072;
    const int q_t = qt * 128 + w * 32 + l31;        // this lane's q row (within b)

    short8 qf[4];
    {
        const u16* qp = Qp + (rowb + q_t) * 1024 + colb + l5 * 8;
#pragma unroll
        for (int ksd = 0; ksd < 4; ++ksd) qf[ksd] = *(const short8*)(qp + ksd * 16);
    }

    int off[4];
#pragma unroll
    for (int ksd = 0; ksd < 4; ++ksd)
        off[ksd] = l31 * 128 + (((ksd * 2 + l5) ^ (l31 & 7)) << 4);

    const float CEXP = 0.18033688011112042f;   // 0.125 * log2(e)
    float mr = -INFINITY;
    f32x16 oacc0 = {}, oacc1 = {}, lacc = {};

    short8 ones;
#pragma unroll
    for (int j = 0; j < 8; ++j) ones[j] = (short)0x3F80;

    const int c0 = tid, c1 = tid + 256;
    const int r0 = c0 >> 3, s0 = (c0 & 7) ^ (r0 & 7);
    const int r1 = c1 >> 3, s1 = (c1 & 7) ^ (r1 & 7);

#define STAGE(buf, t) do {                                                               \
    const long kv0_ = (long)((t) * 64);                                                  \
    gload_lds16(Kbase + (kv0_ + r0) * 1024 + s0 * 8, &Ks[buf][w * 512]);                 \
    gload_lds16(Kbase + (kv0_ + r1) * 1024 + s1 * 8, &Ks[buf][2048 + w * 512]);          \
    gload_lds16(VhT + vbase + (long)r0 * 2048 + kv0_ + s0 * 8, &Vs[buf][w * 512]);       \
    gload_lds16(VhT + vbase + (long)r1 * 2048 + kv0_ + s1 * 8, &Vs[buf][2048 + w * 512]); \
  } while (0)

    STAGE(0, 0);

#pragma unroll 2
    for (int t = 0; t < 32; ++t) {
        const int buf = t & 1;
        __syncthreads();
        if (t < 31) STAGE(buf ^ 1, t + 1);

        const char* Kb = (const char*)&Ks[buf][0];
        const char* Vb = (const char*)&Vs[buf][0];

        f32x16 z0 = {}, z1 = {};
#pragma unroll
        for (int ksd = 0; ksd < 4; ++ksd) {
            short8 kf0 = *(const short8*)(Kb + off[ksd]);
            z0 = __builtin_amdgcn_mfma_f32_32x32x16_bf16(kf0, qf[ksd], z0, 0, 0, 0);
            short8 kf1 = *(const short8*)(Kb + 4096 + off[ksd]);
            z1 = __builtin_amdgcn_mfma_f32_32x32x16_bf16(kf1, qf[ksd], z1, 0, 0, 0);
        }

        float a0 = max3f(z0[0],  z0[1],  z0[2]);
        float a1 = max3f(z0[3],  z0[4],  z0[5]);
        float a2 = max3f(z0[6],  z0[7],  z0[8]);
        float a3 = max3f(z0[9],  z0[10], z0[11]);
        float a4 = max3f(z0[12], z0[13], z0[14]);
        float a5 = max3f(z0[15], z1[0],  z1[1]);
        float a6 = max3f(z1[2],  z1[3],  z1[4]);
        float a7 = max3f(z1[5],  z1[6],  z1[7]);
        float a8 = max3f(z1[8],  z1[9],  z1[10]);
        float a9 = max3f(z1[11], z1[12], z1[13]);
        float aa = fmaxf(z1[14], z1[15]);
        float b0 = max3f(a0, a1, a2);
        float b1 = max3f(a3, a4, a5);
        float b2 = max3f(a6, a7, a8);
        float b3 = fmaxf(a9, aa);
        float vm = fmaxf(max3f(b0, b1, b2), b3);
        {
            u32x2 pp = __builtin_amdgcn_permlane32_swap(__builtin_bit_cast(u32, vm),
                                                        __builtin_bit_cast(u32, vm), false, false);
            vm = fmaxf(__builtin_bit_cast(float, pp[0]), __builtin_bit_cast(float, pp[1]));
        }
        if (!__all(vm - mr <= 8.0f)) {     // T13 defer-max (raw THR=8 -> P <= e)
            const float nm = fmaxf(mr, vm);
            const float sc = exp2_raw((mr - nm) * CEXP);
            mr = nm;
#pragma unroll
            for (int i = 0; i < 16; ++i) { oacc0[i] *= sc; oacc1[i] *= sc; }
            lacc[0] *= sc;
        }
        const float nmc = -mr * CEXP;

#pragma unroll
        for (int tile = 0; tile < 2; ++tile) {
            const f32x16& zz = tile ? z1 : z0;
            u32 W[8];
#pragma unroll
            for (int mw = 0; mw < 8; ++mw) {
                const float p0 = exp2_raw(fmaf(zz[2 * mw],     CEXP, nmc));
                const float p1 = exp2_raw(fmaf(zz[2 * mw + 1], CEXP, nmc));
                W[mw] = cvtpk_bf2(p0, p1);
            }
#pragma unroll
            for (int ksw = 0; ksw < 2; ++ksw) {
                const int ks = tile * 2 + ksw;
                u32x2 ra = __builtin_amdgcn_permlane32_swap(W[4 * ksw + 0], W[4 * ksw + 2], false, false);
                u32x2 rb = __builtin_amdgcn_permlane32_swap(W[4 * ksw + 1], W[4 * ksw + 3], false, false);
                u32x4 pw; pw[0] = ra[0]; pw[1] = rb[0]; pw[2] = ra[1]; pw[3] = rb[1];
                const short8 pb = __builtin_bit_cast(short8, pw);
                short8 vf0 = *(const short8*)(Vb + off[ks]);
                oacc0 = __builtin_amdgcn_mfma_f32_32x32x16_bf16(vf0, pb, oacc0, 0, 0, 0);
                short8 vf1 = *(const short8*)(Vb + 4096 + off[ks]);
                oacc1 = __builtin_amdgcn_mfma_f32_32x32x16_bf16(vf1, pb, oacc1, 0, 0, 0);
                lacc = __builtin_amdgcn_mfma_f32_32x32x16_bf16(ones, pb, lacc, 0, 0, 0);
            }
        }
    }
#undef STAGE

    const float inv = 1.0f / lacc[0];
    u16* op = attn + (rowb + q_t) * 1024 + colb;
#pragma unroll
    for (int et = 0; et < 2; ++et) {
        const f32x16& oa = et ? oacc1 : oacc0;
#pragma unroll
        for (int rq = 0; rq < 4; ++rq) {
            u32x2 st;
            st[0] = cvtpk_bf2(oa[4 * rq + 0] * inv, oa[4 * rq + 1] * inv);
            st[1] = cvtpk_bf2(oa[4 * rq + 2] * inv, oa[4 * rq + 3] * inv);
            *(u32x2*)(op + et * 32 + rq * 8 + l5 * 4) = st;
        }
    }
}

extern "C" void kernel_launch(void* const* d_in, const int* in_sizes, int n_in,
                              void* d_out, int out_size, void* d_ws, size_t ws_size,
                              hipStream_t stream) {
    (void)in_sizes; (void)n_in; (void)out_size; (void)ws_size;
    const float* Q  = (const float*)d_in[0];
    const float* K  = (const float*)d_in[1];
    const float* V  = (const float*)d_in[2];
    const float* Wq = (const float*)d_in[3];
    const float* Wk = (const float*)d_in[4];
    const float* Wv = (const float*)d_in[5];
    const float* Wo = (const float*)d_in[6];

    char* ws = (char*)d_ws;
    auto WS = [&](size_t mb) { return (u16*)(ws + (mb << 20)); };
    u16* WqT  = WS(0);    // [1024 he][1024 d] bf16, 2MB each
    u16* WkT  = WS(2);
    u16* WvT  = WS(4);
    u16* WoT  = WS(6);    // [1024 D][1024 he]
    u16* Xq   = WS(8);    // bf16 [8192][1024], 16MB each
    u16* Xk   = WS(24);
    u16* Xv   = WS(40);
    u16* Qp   = WS(56);   // proj outputs [8192][1024]
    u16* Kp   = WS(72);
    u16* Vp   = WS(88);   // ends 104MB
    u16* VhT  = WS(24);   // [64 bh][64 e][2048 t] — reuses Xk (dead after gemm3)
    u16* attn = WS(8);    // [8192][1024] — reuses Xq (dead after gemm3)

    dim3 b256(256);
    dim3 b512(512);
    // weights -> B^T bf16
    k_transpose_w3<<<dim3(16, 1, 48), b256, 0, stream>>>(Wq, Wk, Wv, WqT, WkT, WvT);
    k_transpose_f32_bf16<<<dim3(16, 16, 1), b256, 0, stream>>>(Wo, WoT, 1024, 1024);
    // inputs -> bf16
    k_cvt3<<<dim3(1024, 1, 3), b256, 0, stream>>>(Q, K, V, Xq, Xk, Xv);

    // merged Q/K/V projections (counted-vmcnt schedule)
    k_gemm3<<<dim3(768), b512, 0, stream>>>(Xq, Xk, Xv, WqT, WkT, WvT, Qp, Kp, Vp);

    // V transpose per (b,h)
    k_transpose_v<<<dim3(32, 1, 64), b256, 0, stream>>>(Vp, VhT);

    // attention
    k_flash4<<<dim3(1024), b256, 0, stream>>>(Qp, Kp, VhT, attn);

    // output projection
    k_gemm_out<<<dim3(256), b512, 0, stream>>>(attn, WoT, (float*)d_out);
}

// Round 8
// 214.760 us; speedup vs baseline: 1.0821x; 1.0678x over previous
//
#include <hip/hip_runtime.h>
#include <hip/hip_bf16.h>

#define DEV __device__ __forceinline__

typedef __attribute__((ext_vector_type(8))) short short8;
typedef __attribute__((ext_vector_type(4))) float f32x4;
typedef __attribute__((ext_vector_type(16))) float f32x16;
typedef __attribute__((ext_vector_type(2))) unsigned int u32x2;
typedef __attribute__((ext_vector_type(4))) unsigned int u32x4;
typedef unsigned short u16;
typedef unsigned int u32;

// B=4, T=2048, D=1024, H=16, E=64, M = B*T = 8192

DEV u16 f2bf(float f) {
    union { __hip_bfloat16 h; u16 u; } cv;
    cv.h = __float2bfloat16(f);
    return cv.u;
}

DEV float exp2_raw(float x) {
    float r;
    asm("v_exp_f32 %0, %1" : "=v"(r) : "v"(x));
    return r;
}

DEV u32 cvtpk_bf2(float lo, float hi) {
    u32 r;
    asm("v_cvt_pk_bf16_f32 %0, %1, %2" : "=v"(r) : "v"(lo), "v"(hi));
    return r;
}

DEV float max3f(float a, float b, float c) { return fmaxf(fmaxf(a, b), c); }

DEV void gload_lds16(const void* g, void* l) {
    __builtin_amdgcn_global_load_lds((const __attribute__((address_space(1))) u32*)g,
                                     (__attribute__((address_space(3))) u32*)l, 16, 0, 0);
}

// ---------- fp32 -> bf16 convert, 3 tensors (8192*1024 each) ----------
__global__ __launch_bounds__(256) void k_cvt3(const float* __restrict__ A0, const float* __restrict__ A1,
                                              const float* __restrict__ A2,
                                              u16* __restrict__ O0, u16* __restrict__ O1,
                                              u16* __restrict__ O2) {
    const int z = blockIdx.z;
    const float* X = z == 0 ? A0 : (z == 1 ? A1 : A2);
    u16* Y = z == 0 ? O0 : (z == 1 ? O1 : O2);
    const int t0 = blockIdx.x * 256 + threadIdx.x;     // 1024 blocks * 256 thr
#pragma unroll
    for (int i = 0; i < 4; ++i) {
        const long c = ((long)i * 262144 + t0) * 8;    // 8 elems/chunk
        float4 v0 = *(const float4*)(X + c);
        float4 v1 = *(const float4*)(X + c + 4);
        u32x4 wv;
        wv[0] = cvtpk_bf2(v0.x, v0.y); wv[1] = cvtpk_bf2(v0.z, v0.w);
        wv[2] = cvtpk_bf2(v1.x, v1.y); wv[3] = cvtpk_bf2(v1.z, v1.w);
        *(u32x4*)(Y + c) = wv;
    }
}

// ---------- transpose fp32 -> bf16 : 3-way merged for Wq/Wk/Wv ----------
__global__ __launch_bounds__(256) void k_transpose_w3(const float* __restrict__ W0,
                                                      const float* __restrict__ W1,
                                                      const float* __restrict__ W2,
                                                      u16* __restrict__ O0,
                                                      u16* __restrict__ O1,
                                                      u16* __restrict__ O2) {
    __shared__ float tile[64][65];
    const int x = threadIdx.x & 63, y = threadIdx.x >> 6;
    const int which = blockIdx.z >> 4, slab_i = blockIdx.z & 15;
    const float* in = which == 0 ? W0 : (which == 1 ? W1 : W2);
    u16* out = which == 0 ? O0 : (which == 1 ? O1 : O2);
    const long slab = (long)slab_i * 1024 * 64;
    const int r0 = blockIdx.x * 64;
#pragma unroll
    for (int i = 0; i < 16; ++i) {
        int rr = y + 4 * i;
        tile[rr][x] = in[slab + (long)(r0 + rr) * 64 + x];
    }
    __syncthreads();
#pragma unroll
    for (int i = 0; i < 16; ++i) {
        int cc = y + 4 * i;
        out[slab + (long)cc * 1024 + (r0 + x)] = f2bf(tile[x][cc]);
    }
}

__global__ __launch_bounds__(256) void k_transpose_f32_bf16(const float* __restrict__ in,
                                                            u16* __restrict__ out,
                                                            int R, int C) {
    __shared__ float tile[64][65];
    const int x = threadIdx.x & 63, y = threadIdx.x >> 6;
    const long slab = (long)blockIdx.z * R * C;
    const int r0 = blockIdx.x * 64, c0 = blockIdx.y * 64;
#pragma unroll
    for (int i = 0; i < 16; ++i) {
        int rr = y + 4 * i;
        tile[rr][x] = in[slab + (long)(r0 + rr) * C + (c0 + x)];
    }
    __syncthreads();
#pragma unroll
    for (int i = 0; i < 16; ++i) {
        int cc = y + 4 * i;
        out[slab + (long)(c0 + cc) * R + (r0 + x)] = f2bf(tile[x][cc]);
    }
}

// ---------- V transpose: Vp [8192][1024] (per bh window) -> VhT [bh][64 e][2048 t] ----------
__global__ __launch_bounds__(256) void k_transpose_v(const u16* __restrict__ Vp,
                                                     u16* __restrict__ VhT) {
    __shared__ u16 tile[64][65];
    const int x = threadIdx.x & 63, y = threadIdx.x >> 6;
    const int bh = blockIdx.z, b = bh >> 4, h = bh & 15;
    const int t0 = blockIdx.x * 64;
#pragma unroll
    for (int i = 0; i < 16; ++i) {
        int rr = y + 4 * i;
        tile[rr][x] = Vp[(long)(b * 2048 + t0 + rr) * 1024 + h * 64 + x];
    }
    __syncthreads();
#pragma unroll
    for (int i = 0; i < 16; ++i) {
        int cc = y + 4 * i;
        VhT[(long)bh * 131072 + (long)cc * 2048 + t0 + x] = tile[x][cc];
    }
}

// ---------- GEMM v3: counted-vmcnt schedule (T3+T4+T5) ----------
template<int CMODE>   // 0: C bf16, 1: C fp32
DEV void gemm8_body(const u16* __restrict__ Ap, const u16* __restrict__ Btp,
                    void* __restrict__ Cp, u16* __restrict__ As, u16* __restrict__ Bs,
                    int brow, int bcol) {
    const int tid = threadIdx.x, lane = tid & 63, w = tid >> 6;
    const int l15 = lane & 15, l4 = lane >> 4;
    const int wr = w >> 1, wc = w & 1;

    const u16* aptr[4]; int adst[4];
#pragma unroll
    for (int i = 0; i < 4; ++i) {
        const int c = i * 512 + w * 64 + lane;
        const int r = c >> 3, s = c & 7, sw = s ^ (r & 7);
        aptr[i] = Ap + (long)(brow + r) * 1024 + sw * 8;
        adst[i] = i * 4096 + w * 512;
    }
    const u16* bptr[2]; int bdst[2];
#pragma unroll
    for (int i = 0; i < 2; ++i) {
        const int c = i * 512 + w * 64 + lane;
        const int r = c >> 3, s = c & 7, sw = s ^ (r & 7);
        bptr[i] = Btp + (long)(bcol + r) * 1024 + sw * 8;
        bdst[i] = i * 4096 + w * 512;
    }

    auto stage = [&](int buf, int kt) {
        const int ko = kt * 64;
        u16* Ad = As + buf * 16384;
        u16* Bd = Bs + buf * 8192;
#pragma unroll
        for (int i = 0; i < 4; ++i) gload_lds16(aptr[i] + ko, Ad + adst[i]);
#pragma unroll
        for (int i = 0; i < 2; ++i) gload_lds16(bptr[i] + ko, Bd + bdst[i]);
    };

    int e4[2];
#pragma unroll
    for (int kk = 0; kk < 2; ++kk) e4[kk] = ((kk * 4 + l4) ^ (l15 & 7)) * 8;
    int offA[4][2], offB[4][2];
#pragma unroll
    for (int m = 0; m < 4; ++m)
#pragma unroll
        for (int kk = 0; kk < 2; ++kk) {
            offA[m][kk] = (wr * 64 + m * 16 + l15) * 64 + e4[kk];
            offB[m][kk] = (wc * 64 + m * 16 + l15) * 64 + e4[kk];
        }

    f32x4 acc[4][4] = {};
    stage(0, 0);
    stage(1, 1);          // 12 loads in flight

    for (int t = 0; t < 16; ++t) {
        const int buf = t & 1;
        if (t < 15) asm volatile("s_waitcnt vmcnt(6)" ::: "memory");
        else        asm volatile("s_waitcnt vmcnt(0)" ::: "memory");
        __builtin_amdgcn_sched_barrier(0);
        __builtin_amdgcn_s_barrier();
        __builtin_amdgcn_sched_barrier(0);

        const u16* Ab = As + buf * 16384;
        const u16* Bb = Bs + buf * 8192;
#pragma unroll
        for (int kk = 0; kk < 2; ++kk) {
            short8 af[4], bfv[4];
#pragma unroll
            for (int m = 0; m < 4; ++m) af[m] = *(const short8*)&Ab[offA[m][kk]];
#pragma unroll
            for (int n = 0; n < 4; ++n) bfv[n] = *(const short8*)&Bb[offB[n][kk]];
            asm volatile("s_waitcnt lgkmcnt(0)" ::: "memory");
            __builtin_amdgcn_sched_barrier(0);
            __builtin_amdgcn_s_setprio(1);
#pragma unroll
            for (int m = 0; m < 4; ++m)
#pragma unroll
                for (int n = 0; n < 4; ++n)
                    acc[m][n] = __builtin_amdgcn_mfma_f32_16x16x32_bf16(af[m], bfv[n], acc[m][n], 0, 0, 0);
            __builtin_amdgcn_s_setprio(0);
            __builtin_amdgcn_sched_barrier(0);
        }
        __builtin_amdgcn_s_barrier();
        __builtin_amdgcn_sched_barrier(0);
        if (t + 2 < 16) stage(buf, t + 2);
    }

#pragma unroll
    for (int m = 0; m < 4; ++m)
#pragma unroll
        for (int n = 0; n < 4; ++n)
#pragma unroll
            for (int r = 0; r < 4; ++r) {
                const long row = brow + wr * 64 + m * 16 + l4 * 4 + r;
                const int col = bcol + wc * 64 + n * 16 + l15;
                if (CMODE == 0) ((u16*)Cp)[row * 1024 + col] = f2bf(acc[m][n][r]);
                else            ((float*)Cp)[row * 1024 + col] = acc[m][n][r];
            }
}

__global__ __launch_bounds__(512) void k_gemm3(const u16* __restrict__ Xq, const u16* __restrict__ Xk,
                                               const u16* __restrict__ Xv,
                                               const u16* __restrict__ B0, const u16* __restrict__ B1,
                                               const u16* __restrict__ B2,
                                               u16* __restrict__ C0, u16* __restrict__ C1,
                                               u16* __restrict__ C2) {
    __shared__ u16 As[2 * 16384];
    __shared__ u16 Bs[2 * 8192];
    const int hw = blockIdx.x;
    const int lg = (hw & 7) * 96 + (hw >> 3);      // bijective: 768 % 8 == 0
    const int z = lg >> 8, rem = lg & 255;
    const int brow = (rem >> 3) * 256, bcol = (rem & 7) * 128;
    const u16* A = z == 0 ? Xq : (z == 1 ? Xk : Xv);
    const u16* Bt = z == 0 ? B0 : (z == 1 ? B1 : B2);
    u16*       C = z == 0 ? C0 : (z == 1 ? C1 : C2);
    gemm8_body<0>(A, Bt, C, As, Bs, brow, bcol);
}

__global__ __launch_bounds__(512) void k_gemm_out(const u16* __restrict__ Ab,
                                                  const u16* __restrict__ Bt,
                                                  float* __restrict__ Cf) {
    __shared__ u16 As[2 * 16384];
    __shared__ u16 Bs[2 * 8192];
    const int hw = blockIdx.x;
    const int lg = (hw & 7) * 32 + (hw >> 3);      // 256 % 8 == 0
    const int brow = (lg >> 3) * 256, bcol = (lg & 7) * 128;
    gemm8_body<1>(Ab, Bt, Cf, As, Bs, brow, bcol);
}

// ---------- flash v5: 64 q-rows/wave — K/V LDS reads amortized over 2 q-groups ----------
// grid 512 = 64 bh * 8 qtiles (XCD-swizzled); 4 waves * 64 q.
// Swapped 32x32 MFMAs; in-register softmax; denominator via f32 pack-time sums
// (no ones-MFMA). Q in regs (2 groups); K/V staged once, frags reused by both groups.
__global__ __launch_bounds__(256, 2) void k_flash5(const u16* __restrict__ Qp,
                                                   const u16* __restrict__ Kp,
                                                   const u16* __restrict__ VhT,
                                                   u16* __restrict__ attn) {
    __shared__ u16 Ks[2][4096];   // [kv][d], 16B chunks XOR-swizzled by row&7
    __shared__ u16 Vs[2][4096];   // [e][kv], same swizzle

    const int tid = threadIdx.x, lane = tid & 63, w = tid >> 6;
    const int l31 = lane & 31, l5 = lane >> 5;
    const int wid = blockIdx.x;
    const int swz = (wid & 7) * 64 + (wid >> 3);    // bijective: 512 % 8 == 0
    const int bh = swz >> 3, qt = swz & 7;
    const int b = bh >> 4, h = bh & 15;
    const long rowb = (long)b * 2048;
    const int colb = h * 64;
    const u16* Kbase = Kp + rowb * 1024 + colb;
    const long vbase = (long)bh * 131072;
    const int q0 = qt * 256 + w * 64;               // wave's q base (within b)

    short8 qf0[4], qf1[4];
#pragma unroll
    for (int ksd = 0; ksd < 4; ++ksd) {
        qf0[ksd] = *(const short8*)(Qp + (rowb + q0 + l31) * 1024 + colb + ksd * 16 + l5 * 8);
        qf1[ksd] = *(const short8*)(Qp + (rowb + q0 + 32 + l31) * 1024 + colb + ksd * 16 + l5 * 8);
    }

    int off[4];
#pragma unroll
    for (int ksd = 0; ksd < 4; ++ksd)
        off[ksd] = l31 * 128 + (((ksd * 2 + l5) ^ (l31 & 7)) << 4);

    const float CEXP = 0.18033688011112042f;   // 0.125 * log2(e)
    float mr0 = -INFINITY, mr1 = -INFINITY, lr0 = 0.f, lr1 = 0.f;
    f32x16 oa00 = {}, oa01 = {}, oa10 = {}, oa11 = {};

    const int c0 = tid, c1 = tid + 256;
    const int r0 = c0 >> 3, s0 = (c0 & 7) ^ (r0 & 7);
    const int r1 = c1 >> 3, s1 = (c1 & 7) ^ (r1 & 7);

#define STAGE(buf, t) do {                                                               \
    const long kv0_ = (long)((t) * 64);                                                  \
    gload_lds16(Kbase + (kv0_ + r0) * 1024 + s0 * 8, &Ks[buf][w * 512]);                 \
    gload_lds16(Kbase + (kv0_ + r1) * 1024 + s1 * 8, &Ks[buf][2048 + w * 512]);          \
    gload_lds16(VhT + vbase + (long)r0 * 2048 + kv0_ + s0 * 8, &Vs[buf][w * 512]);       \
    gload_lds16(VhT + vbase + (long)r1 * 2048 + kv0_ + s1 * 8, &Vs[buf][2048 + w * 512]); \
  } while (0)

    // row max over 32 scores (two f32x16), then cross-half swap
    auto rowmax = [&](const f32x16& za, const f32x16& zb) -> float {
        float a0 = max3f(za[0],  za[1],  za[2]);
        float a1 = max3f(za[3],  za[4],  za[5]);
        float a2 = max3f(za[6],  za[7],  za[8]);
        float a3 = max3f(za[9],  za[10], za[11]);
        float a4 = max3f(za[12], za[13], za[14]);
        float a5 = max3f(za[15], zb[0],  zb[1]);
        float a6 = max3f(zb[2],  zb[3],  zb[4]);
        float a7 = max3f(zb[5],  zb[6],  zb[7]);
        float a8 = max3f(zb[8],  zb[9],  zb[10]);
        float a9 = max3f(zb[11], zb[12], zb[13]);
        float aa = fmaxf(zb[14], zb[15]);
        float b0 = max3f(a0, a1, a2);
        float b1 = max3f(a3, a4, a5);
        float b2 = max3f(a6, a7, a8);
        float b3 = fmaxf(a9, aa);
        float vm = fmaxf(max3f(b0, b1, b2), b3);
        u32x2 pp = __builtin_amdgcn_permlane32_swap(__builtin_bit_cast(u32, vm),
                                                    __builtin_bit_cast(u32, vm), false, false);
        return fmaxf(__builtin_bit_cast(float, pp[0]), __builtin_bit_cast(float, pp[1]));
    };

    // softmax one group: update (mr, lr, oa pair), emit pb[4]
    auto process = [&](const f32x16& za, const f32x16& zb, float& mr, float& lr,
                       f32x16& oaA, f32x16& oaB, short8* pb) {
        const float vm = rowmax(za, zb);
        if (!__all(vm - mr <= 8.0f)) {     // T13 defer-max (raw THR=8 -> P <= e)
            const float nm = fmaxf(mr, vm);
            const float sc = exp2_raw((mr - nm) * CEXP);
            mr = nm;
#pragma unroll
            for (int i = 0; i < 16; ++i) { oaA[i] *= sc; oaB[i] *= sc; }
            lr *= sc;
        }
        const float nmc = -mr * CEXP;
        float rs = 0.f;
#pragma unroll
        for (int tile = 0; tile < 2; ++tile) {
            const f32x16& zz = tile ? zb : za;
            u32 W[8];
#pragma unroll
            for (int mw = 0; mw < 8; ++mw) {
                const float p0 = exp2_raw(fmaf(zz[2 * mw],     CEXP, nmc));
                const float p1 = exp2_raw(fmaf(zz[2 * mw + 1], CEXP, nmc));
                rs += p0 + p1;
                W[mw] = cvtpk_bf2(p0, p1);
            }
#pragma unroll
            for (int ksw = 0; ksw < 2; ++ksw) {
                u32x2 ra = __builtin_amdgcn_permlane32_swap(W[4 * ksw + 0], W[4 * ksw + 2], false, false);
                u32x2 rb = __builtin_amdgcn_permlane32_swap(W[4 * ksw + 1], W[4 * ksw + 3], false, false);
                u32x4 pw; pw[0] = ra[0]; pw[1] = rb[0]; pw[2] = ra[1]; pw[3] = rb[1];
                pb[tile * 2 + ksw] = __builtin_bit_cast(short8, pw);
            }
        }
        u32x2 rr = __builtin_amdgcn_permlane32_swap(__builtin_bit_cast(u32, rs),
                                                    __builtin_bit_cast(u32, rs), false, false);
        lr += __builtin_bit_cast(float, rr[0]) + __builtin_bit_cast(float, rr[1]);
    };

    STAGE(0, 0);

#pragma unroll 2
    for (int t = 0; t < 32; ++t) {
        const int buf = t & 1;
        __syncthreads();
        if (t < 31) STAGE(buf ^ 1, t + 1);

        const char* Kb = (const char*)&Ks[buf][0];
        const char* Vb = (const char*)&Vs[buf][0];

        // ---- QK^T both groups, K frags loaded once
        f32x16 z0a = {}, z0b = {}, z1a = {}, z1b = {};
#pragma unroll
        for (int ksd = 0; ksd < 4; ++ksd) {
            short8 kf0 = *(const short8*)(Kb + off[ksd]);
            short8 kf1 = *(const short8*)(Kb + 4096 + off[ksd]);
            z0a = __builtin_amdgcn_mfma_f32_32x32x16_bf16(kf0, qf0[ksd], z0a, 0, 0, 0);
            z0b = __builtin_amdgcn_mfma_f32_32x32x16_bf16(kf1, qf0[ksd], z0b, 0, 0, 0);
            z1a = __builtin_amdgcn_mfma_f32_32x32x16_bf16(kf0, qf1[ksd], z1a, 0, 0, 0);
            z1b = __builtin_amdgcn_mfma_f32_32x32x16_bf16(kf1, qf1[ksd], z1b, 0, 0, 0);
        }

        short8 pb0[4], pb1[4];
        process(z0a, z0b, mr0, lr0, oa00, oa01, pb0);
        process(z1a, z1b, mr1, lr1, oa10, oa11, pb1);

        // ---- PV both groups, V frags loaded once
#pragma unroll
        for (int ks = 0; ks < 4; ++ks) {
            short8 vf0 = *(const short8*)(Vb + off[ks]);
            short8 vf1 = *(const short8*)(Vb + 4096 + off[ks]);
            oa00 = __builtin_amdgcn_mfma_f32_32x32x16_bf16(vf0, pb0[ks], oa00, 0, 0, 0);
            oa01 = __builtin_amdgcn_mfma_f32_32x32x16_bf16(vf1, pb0[ks], oa01, 0, 0, 0);
            oa10 = __builtin_amdgcn_mfma_f32_32x32x16_bf16(vf0, pb1[ks], oa10, 0, 0, 0);
            oa11 = __builtin_amdgcn_mfma_f32_32x32x16_bf16(vf1, pb1[ks], oa11, 0, 0, 0);
        }
    }
#undef STAGE

    // ---- epilogue: O^T lane layout: q = l31 (per group), e = (reg&3)+8*(reg>>2)+4*l5
#pragma unroll
    for (int g = 0; g < 2; ++g) {
        const float inv = 1.0f / (g ? lr1 : lr0);
        u16* op = attn + (rowb + q0 + g * 32 + l31) * 1024 + colb;
#pragma unroll
        for (int et = 0; et < 2; ++et) {
            const f32x16& oa = g ? (et ? oa11 : oa10) : (et ? oa01 : oa00);
#pragma unroll
            for (int rq = 0; rq < 4; ++rq) {
                u32x2 st;
                st[0] = cvtpk_bf2(oa[4 * rq + 0] * inv, oa[4 * rq + 1] * inv);
                st[1] = cvtpk_bf2(oa[4 * rq + 2] * inv, oa[4 * rq + 3] * inv);
                *(u32x2*)(op + et * 32 + rq * 8 + l5 * 4) = st;
            }
        }
    }
}

extern "C" void kernel_launch(void* const* d_in, const int* in_sizes, int n_in,
                              void* d_out, int out_size, void* d_ws, size_t ws_size,
                              hipStream_t stream) {
    (void)in_sizes; (void)n_in; (void)out_size; (void)ws_size;
    const float* Q  = (const float*)d_in[0];
    const float* K  = (const float*)d_in[1];
    const float* V  = (const float*)d_in[2];
    const float* Wq = (const float*)d_in[3];
    const float* Wk = (const float*)d_in[4];
    const float* Wv = (const float*)d_in[5];
    const float* Wo = (const float*)d_in[6];

    char* ws = (char*)d_ws;
    auto WS = [&](size_t mb) { return (u16*)(ws + (mb << 20)); };
    u16* WqT  = WS(0);    // [1024 he][1024 d] bf16, 2MB each
    u16* WkT  = WS(2);
    u16* WvT  = WS(4);
    u16* WoT  = WS(6);    // [1024 D][1024 he]
    u16* Xq   = WS(8);    // bf16 [8192][1024], 16MB each
    u16* Xk   = WS(24);
    u16* Xv   = WS(40);
    u16* Qp   = WS(56);   // proj outputs [8192][1024]
    u16* Kp   = WS(72);
    u16* Vp   = WS(88);   // ends 104MB
    u16* VhT  = WS(24);   // [64 bh][64 e][2048 t] — reuses Xk (dead after gemm3)
    u16* attn = WS(8);    // [8192][1024] — reuses Xq (dead after gemm3)

    dim3 b256(256);
    dim3 b512(512);
    // weights -> B^T bf16
    k_transpose_w3<<<dim3(16, 1, 48), b256, 0, stream>>>(Wq, Wk, Wv, WqT, WkT, WvT);
    k_transpose_f32_bf16<<<dim3(16, 16, 1), b256, 0, stream>>>(Wo, WoT, 1024, 1024);
    // inputs -> bf16
    k_cvt3<<<dim3(1024, 1, 3), b256, 0, stream>>>(Q, K, V, Xq, Xk, Xv);

    // merged Q/K/V projections (counted-vmcnt schedule)
    k_gemm3<<<dim3(768), b512, 0, stream>>>(Xq, Xk, Xv, WqT, WkT, WvT, Qp, Kp, Vp);

    // V transpose per (b,h)
    k_transpose_v<<<dim3(32, 1, 64), b256, 0, stream>>>(Vp, VhT);

    // attention
    k_flash5<<<dim3(512), b256, 0, stream>>>(Qp, Kp, VhT, attn);

    // output projection
    k_gemm_out<<<dim3(256), b512, 0, stream>>>(attn, WoT, (float*)d_out);
}